// Round 11
// baseline (230.558 us; speedup 1.0000x reference)
//
#include <hip/hip_runtime.h>

#define NT 8
#define ND 16
#define NH 16
#define NW 16
#define NC 32
#define NB 65536
#define NCELLS (5 * 13 * 13)   // 845 span-base cells (t,d,h)
#define CAP 1024               // per-cell perm slab (expected max ~333)
#define CHUNKQ 64              // queries per main block
#define NCHUNKS_PER_CELL (CAP / CHUNKQ)   // 16

typedef __attribute__((ext_vector_type(8))) _Float16 half8;
typedef __attribute__((ext_vector_type(4))) _Float16 half4;
typedef __attribute__((ext_vector_type(2))) _Float16 half2v;

union H8 {
    half8 v;
    half2v h2[4];
};

// ---- shared span-base logic (IDENTICAL in binning + main) ----
template <int N>
__device__ __forceinline__ int span_base(float u) {
    float s = u * (float)(N - 1);
    float fi = fminf(fmaxf(floorf(s), 0.0f), (float)(N - 2));
    int i = (int)fi;
    return (i == 0) ? 0 : ((i == N - 2) ? (N - 4) : (i - 1));
}

// Span-based per-dim setup: span b..b+3 (in-bounds) + 4 weights with the
// linear-extrapolation padding folded in. Validated rounds 3-10 (absmax 7.8e-3).
template <int N>
__device__ __forceinline__ void dim_setup_span(float u, int& b, float w[4]) {
    float s = u * (float)(N - 1);
    float fi = fminf(fmaxf(floorf(s), 0.0f), (float)(N - 2));
    float t = s - fi;
    int i = (int)fi;
    float t2 = t * t, t3 = t2 * t;
    const float c6 = 1.0f / 6.0f;
    float w0 = (1.0f - 3.0f * t + 3.0f * t2 - t3) * c6;
    float w1 = (4.0f - 6.0f * t2 + 3.0f * t3) * c6;
    float w2 = (1.0f + 3.0f * t + 3.0f * t2 - 3.0f * t3) * c6;
    float w3 = t3 * c6;
    if (i == 0) {
        b = 0;
        w[0] = w1 + 2.0f * w0; w[1] = w2 - w0; w[2] = w3; w[3] = 0.0f;
    } else if (i == N - 2) {
        b = N - 4;
        w[0] = 0.0f; w[1] = w0; w[2] = w1 - w3; w[3] = w2 + 2.0f * w3;
    } else {
        b = i - 1;
        w[0] = w0; w[1] = w1; w[2] = w2; w[3] = w3;
    }
}

// ---- fused prep: f32->fp16 convert (blocks 0..1023) + count/perm (1024..1279)
// perm is a fixed-capacity slab per cell: no scan, no scatter kernel needed.
// Output is rank-order independent (each q computed identically wherever it
// lands), so atomicAdd nondeterminism does not affect results.
__global__ __launch_bounds__(256) void prep_kernel(
    const float4* __restrict__ g, half4* __restrict__ hg,
    const float4* __restrict__ u4, int* __restrict__ count,
    int* __restrict__ perm) {
    int b = blockIdx.x;
    int t = threadIdx.x;
    if (b < 1024) {
        int i = b * 256 + t;
        float4 v = g[i];
        half4 h;
        h[0] = (_Float16)v.x;
        h[1] = (_Float16)v.y;
        h[2] = (_Float16)v.z;
        h[3] = (_Float16)v.w;
        hg[i] = h;
    } else {
        int q = (b - 1024) * 256 + t;
        float4 uu = u4[q];
        int bt = span_base<NT>(uu.x);
        int bd = span_base<ND>(uu.y);
        int bh = span_base<NH>(uu.z);
        int cell = (bt * 13 + bd) * 13 + bh;
        int rank = atomicAdd(&count[cell], 1);
        if (rank < CAP) perm[cell * CAP + rank] = q;
    }
}

// ---- main: grid = NCELLS*16 blocks; block = cell's chunk of <=64 queries.
// 1024 threads (64 slots x 16 lanes), 64KB LDS -> 2 blocks/CU = 32 waves/CU.
// Stage the cell's 4x4x4-row region (64 rows x 1KB) via global_load_lds
// (linear dest: consecutive threads -> consecutive 16B, required pattern).
__global__ __launch_bounds__(1024, 8) void spline4d_cell_kernel(
    const float* __restrict__ u, const uint4* __restrict__ hgrid,
    const int* __restrict__ count, const int* __restrict__ perm,
    float4* __restrict__ out) {
    int cell = blockIdx.x >> 4;
    int kch = blockIdx.x & (NCHUNKS_PER_CELL - 1);
    int n = min(count[cell], CAP);
    int start = kch * CHUNKQ;
    if (start >= n) return;      // empty chunk: exit before staging
    int len = min(CHUNKQ, n - start);

    __shared__ uint4 smem[4096];   // 64 KB: 64 rows x 1KB

    int bt = cell / 169;
    int r0 = cell - bt * 169;
    int bd = r0 / 13;
    int bh = r0 - bd * 13;

    // stage 64 rows (i,j,k), each 1KB (16 w-points x 64B): 4 iters/thread
    for (int idx = (int)threadIdx.x; idx < 4096; idx += 1024) {
        int lrow = idx >> 6;
        int chunk = idx & 63;
        int i = lrow >> 4, j = (lrow >> 2) & 3, k = lrow & 3;
        int R = ((bt + i) * ND + (bd + j)) * NH + (bh + k);
#if __has_builtin(__builtin_amdgcn_global_load_lds)
        __builtin_amdgcn_global_load_lds(
            (const __attribute__((address_space(1))) uint32_t*)(&hgrid[R * 64 + chunk]),
            (__attribute__((address_space(3))) uint32_t*)(&smem[idx]),
            16, 0, 0);
#else
        smem[idx] = hgrid[R * 64 + chunk];
#endif
    }
    __syncthreads();

    int slot = (int)threadIdx.x >> 4;
    int s = (int)threadIdx.x & 15;
    if (slot >= len) return;

    const half8* slds = reinterpret_cast<const half8*>(smem);
    int q = perm[cell * CAP + start + slot];

    float4 uu = reinterpret_cast<const float4*>(u)[q];

    int xbt, xbd, xbh, bw;
    float wtv[4], wdv[4], whv[4], wwv[4];
    dim_setup_span<NT>(uu.x, xbt, wtv);
    dim_setup_span<ND>(uu.y, xbd, wdv);
    dim_setup_span<NH>(uu.z, xbh, whv);
    dim_setup_span<NW>(uu.w, bw, wwv);
    // xbt==bt etc. by construction

    int wp = s >> 2;
    float wlane = (wp & 2) ? ((wp & 1) ? wwv[3] : wwv[2])
                           : ((wp & 1) ? wwv[1] : wwv[0]);

    half2v whW2[4];
#pragma unroll
    for (int k = 0; k < 4; ++k) {
        _Float16 h = (_Float16)(whv[k] * wlane);
        whW2[k][0] = h;
        whW2[k][1] = h;
    }

    float facc[8];
#pragma unroll
    for (int c = 0; c < 8; ++c) facc[c] = 0.0f;
    half2v a01 = {0, 0}, a23 = {0, 0}, a45 = {0, 0}, a67 = {0, 0};

    int lbase = (bw << 2) + s;

#pragma unroll
    for (int i = 0; i < 4; ++i) {
#pragma unroll
        for (int j = 0; j < 4; ++j) {
            _Float16 wtdh = (_Float16)(wtv[i] * wdv[j]);
            half2v wtd2 = {wtdh, wtdh};
#pragma unroll
            for (int k = 0; k < 4; ++k) {
                int lidx = ((i << 4) + (j << 2) + k) * 64 + lbase;
                H8 P;
                P.v = slds[lidx];
                half2v uw = wtd2 * whW2[k];
                a01 += P.h2[0] * uw;
                a23 += P.h2[1] * uw;
                a45 += P.h2[2] * uw;
                a67 += P.h2[3] * uw;
            }
        }
        if (i == 1 || i == 3) {
            facc[0] += (float)a01[0]; facc[1] += (float)a01[1];
            facc[2] += (float)a23[0]; facc[3] += (float)a23[1];
            facc[4] += (float)a45[0]; facc[5] += (float)a45[1];
            facc[6] += (float)a67[0]; facc[7] += (float)a67[1];
            a01 = (half2v){0, 0}; a23 = (half2v){0, 0};
            a45 = (half2v){0, 0}; a67 = (half2v){0, 0};
        }
    }

#pragma unroll
    for (int c = 0; c < 8; ++c) {
        facc[c] += __shfl_xor(facc[c], 4);
        facc[c] += __shfl_xor(facc[c], 8);
    }

    if (s < 4) {
        out[q * 8 + s * 2] = make_float4(facc[0], facc[1], facc[2], facc[3]);
        out[q * 8 + s * 2 + 1] = make_float4(facc[4], facc[5], facc[6], facc[7]);
    }
}

// ---- fallback (ws too small for perm slab): round-6 direct fp16, 52.5us ----
__global__ __launch_bounds__(256) void convert_fp16_kernel(
    const float4* __restrict__ g, half4* __restrict__ hg) {
    int i = blockIdx.x * blockDim.x + threadIdx.x;
    float4 v = g[i];
    half4 h;
    h[0] = (_Float16)v.x;
    h[1] = (_Float16)v.y;
    h[2] = (_Float16)v.z;
    h[3] = (_Float16)v.w;
    hg[i] = h;
}

__global__ __launch_bounds__(256) void spline4d_fp16_kernel(
    const float* __restrict__ u, const half8* __restrict__ grid,
    float4* __restrict__ out) {
    int tid = blockIdx.x * blockDim.x + threadIdx.x;
    int q = tid >> 4;
    int s = tid & 15;

    float4 uu = reinterpret_cast<const float4*>(u)[q];

    int bt, bd, bh, bw;
    float wtv[4], wdv[4], whv[4], wwv[4];
    dim_setup_span<NT>(uu.x, bt, wtv);
    dim_setup_span<ND>(uu.y, bd, wdv);
    dim_setup_span<NH>(uu.z, bh, whv);
    dim_setup_span<NW>(uu.w, bw, wwv);

    int wp = s >> 2;
    float wlane = (wp & 2) ? ((wp & 1) ? wwv[3] : wwv[2])
                           : ((wp & 1) ? wwv[1] : wwv[0]);

    half2v whW2[4];
#pragma unroll
    for (int k = 0; k < 4; ++k) {
        _Float16 h = (_Float16)(whv[k] * wlane);
        whW2[k][0] = h;
        whW2[k][1] = h;
    }

    int base = ((((bt * ND + bd) * NH + bh) * NW + bw) << 2) + s;

    float facc[8];
#pragma unroll
    for (int c = 0; c < 8; ++c) facc[c] = 0.0f;
    half2v a01 = {0, 0}, a23 = {0, 0}, a45 = {0, 0}, a67 = {0, 0};

#pragma unroll
    for (int i = 0; i < 4; ++i) {
#pragma unroll
        for (int j = 0; j < 4; ++j) {
            _Float16 wtdh = (_Float16)(wtv[i] * wdv[j]);
            half2v wtd2 = {wtdh, wtdh};
#pragma unroll
            for (int k = 0; k < 4; ++k) {
                int a = base + i * (4 * ND * NH * NW) + j * (4 * NH * NW) +
                        k * (4 * NW);
                H8 P;
                P.v = grid[a];
                half2v uw = wtd2 * whW2[k];
                a01 += P.h2[0] * uw;
                a23 += P.h2[1] * uw;
                a45 += P.h2[2] * uw;
                a67 += P.h2[3] * uw;
            }
        }
        if (i == 1 || i == 3) {
            facc[0] += (float)a01[0]; facc[1] += (float)a01[1];
            facc[2] += (float)a23[0]; facc[3] += (float)a23[1];
            facc[4] += (float)a45[0]; facc[5] += (float)a45[1];
            facc[6] += (float)a67[0]; facc[7] += (float)a67[1];
            a01 = (half2v){0, 0}; a23 = (half2v){0, 0};
            a45 = (half2v){0, 0}; a67 = (half2v){0, 0};
        }
    }

#pragma unroll
    for (int c = 0; c < 8; ++c) {
        facc[c] += __shfl_xor(facc[c], 4);
        facc[c] += __shfl_xor(facc[c], 8);
    }

    if (s < 4) {
        out[q * 8 + s * 2] = make_float4(facc[0], facc[1], facc[2], facc[3]);
        out[q * 8 + s * 2 + 1] = make_float4(facc[4], facc[5], facc[6], facc[7]);
    }
}

extern "C" void kernel_launch(void* const* d_in, const int* in_sizes, int n_in,
                              void* d_out, int out_size, void* d_ws, size_t ws_size,
                              hipStream_t stream) {
    const float* u = (const float*)d_in[0];
    const float* grid_f32 = (const float*)d_in[1];
    float4* out = (float4*)d_out;

    const size_t n_grid_floats = (size_t)NT * ND * NH * NW * NC;  // 1,048,576
    const size_t HG_BYTES = n_grid_floats * 2;                    // 2 MiB

    // workspace layout
    char* ws = (char*)d_ws;
    const size_t OFF_COUNT = HG_BYTES;                       // 8 KB reserve
    const size_t OFF_PERM = OFF_COUNT + 8192;                // 845*1024*4
    const size_t NEED = OFF_PERM + (size_t)NCELLS * CAP * 4; // ~5.47 MB

    if (ws_size >= NEED) {
        half4* hgrid = (half4*)ws;
        int* count = (int*)(ws + OFF_COUNT);
        int* perm = (int*)(ws + OFF_PERM);

        hipMemsetAsync(count, 0, 8192, stream);
        prep_kernel<<<1024 + NB / 256, 256, 0, stream>>>(
            (const float4*)grid_f32, hgrid, (const float4*)u, count, perm);
        spline4d_cell_kernel<<<NCELLS * NCHUNKS_PER_CELL, 1024, 0, stream>>>(
            u, (const uint4*)hgrid, count, perm, out);
    } else if (ws_size >= HG_BYTES) {
        half4* hgrid = (half4*)ws;
        int cvt_blocks = (int)(n_grid_floats / 4 / 256);  // 1024
        convert_fp16_kernel<<<cvt_blocks, 256, 0, stream>>>(
            (const float4*)grid_f32, hgrid);
        int nblocks = NB * 16 / 256;
        spline4d_fp16_kernel<<<nblocks, 256, 0, stream>>>(
            u, (const half8*)hgrid, out);
    }
}